// Round 3
// baseline (1443.406 us; speedup 1.0000x reference)
//
#include <hip/hip_runtime.h>

__device__ __forceinline__ int swz(int c) { return c ^ (((c >> 5) & 3) << 2); }

// ---------------- prep: motif prefix offsets + batch boundaries ----------------
__global__ void prep_kernel(const int* __restrict__ num_motifs,
                            const int* __restrict__ batch,
                            int N, int B,
                            int* __restrict__ partial,
                            int* __restrict__ bnd) {
  int t = threadIdx.x;
  if (t == 0) {
    int s = 0;
    for (int b = 0; b < B; ++b) { partial[b] = s; s += num_motifs[b]; }
  }
  if (t <= B) {  // lower_bound(batch, t) over sorted batch
    int lo = 0, hi = N;
    while (lo < hi) { int mid = (lo + hi) >> 1; if (batch[mid] < t) lo = mid + 1; else hi = mid; }
    bnd[t] = lo;
  }
}

// ---------------- CSR build: histogram -> scan -> scatter ----------------
__global__ __launch_bounds__(256) void hist_kernel(const int* __restrict__ dst, int E,
                                                   int* __restrict__ counts) {
  int e = blockIdx.x * 256 + threadIdx.x;
  if (e < E) atomicAdd(&counts[dst[e]], 1);
}

// single block, 1024 threads: exclusive scan counts[0..n) -> base[0..n], cursor=base copy
__global__ __launch_bounds__(1024) void scan_kernel(const int* __restrict__ counts, int n,
                                                    int* __restrict__ base,
                                                    int* __restrict__ cursor) {
  __shared__ int part[1024];
  const int tid = threadIdx.x;
  const int chunk = (n + 1023) / 1024;
  const int lo = tid * chunk;
  const int hi = min(lo + chunk, n);
  int s = 0;
  for (int i = lo; i < hi; ++i) s += counts[i];
  part[tid] = s;
  __syncthreads();
  for (int off = 1; off < 1024; off <<= 1) {
    int v = (tid >= off) ? part[tid - off] : 0;
    __syncthreads();
    part[tid] += v;
    __syncthreads();
  }
  int run = (tid > 0) ? part[tid - 1] : 0;   // exclusive prefix of this chunk
  for (int i = lo; i < hi; ++i) {
    base[i] = run; cursor[i] = run;
    run += counts[i];
  }
  if (tid == 1023) base[n] = part[1023];
}

__global__ __launch_bounds__(256) void scatter_kernel(const int* __restrict__ src,
                                                      const int* __restrict__ dst, int E,
                                                      int* __restrict__ cursor,
                                                      int* __restrict__ eid_s,
                                                      int* __restrict__ src_s) {
  int e = blockIdx.x * 256 + threadIdx.x;
  if (e >= E) return;
  int d = dst[e];
  int pos = atomicAdd(&cursor[d], 1);
  eid_s[pos] = e;
  src_s[pos] = src[e];
}

// ---- GINE pull-aggregate fused with self: h[n,d] = x[n,d] + sum_e relu(x[src_e,d]+ea[e,d]) ----
__global__ __launch_bounds__(128) void gine_agg_kernel(
    const float* __restrict__ x, const float* __restrict__ ea,
    const int* __restrict__ base, const int* __restrict__ eid_s,
    const int* __restrict__ src_s, float* __restrict__ h, int N) {
  const int n = blockIdx.x * 2 + (threadIdx.x >> 6);
  if (n >= N) return;
  const int d2 = (threadIdx.x & 63) * 2;
  const int e0 = base[n], e1 = base[n + 1];
  float sx = 0.f, sy = 0.f;
  int j = e0;
  for (; j + 1 < e1; j += 2) {
    int eA = eid_s[j],     sA = src_s[j];
    int eB = eid_s[j + 1], sB = src_s[j + 1];
    float2 xa = *(const float2*)&x[sA * 128 + d2];
    float2 ja = *(const float2*)&ea[eA * 128 + d2];
    float2 xb = *(const float2*)&x[sB * 128 + d2];
    float2 jb = *(const float2*)&ea[eB * 128 + d2];
    sx += fmaxf(xa.x + ja.x, 0.f) + fmaxf(xb.x + jb.x, 0.f);
    sy += fmaxf(xa.y + ja.y, 0.f) + fmaxf(xb.y + jb.y, 0.f);
  }
  if (j < e1) {
    float2 xa = *(const float2*)&x[src_s[j] * 128 + d2];
    float2 ja = *(const float2*)&ea[eid_s[j] * 128 + d2];
    sx += fmaxf(xa.x + ja.x, 0.f);
    sy += fmaxf(xa.y + ja.y, 0.f);
  }
  float2 xv = *(const float2*)&x[n * 128 + d2];
  *(float2*)&h[n * 128 + d2] = make_float2(xv.x + sx, xv.y + sy);
}

// ---- GIN pull-aggregate fused with self: ho[m,d] = hi[m,d] + sum_e hi[src_e,d] ----
__global__ __launch_bounds__(128) void gin_agg_kernel(
    const float* __restrict__ hi, const int* __restrict__ base,
    const int* __restrict__ src_s, float* __restrict__ ho, int M) {
  const int m = blockIdx.x * 2 + (threadIdx.x >> 6);
  if (m >= M) return;
  const int d2 = (threadIdx.x & 63) * 2;
  const int e0 = base[m], e1 = base[m + 1];
  float sx = 0.f, sy = 0.f;
  int j = e0;
  for (; j + 1 < e1; j += 2) {
    float2 a = *(const float2*)&hi[src_s[j] * 128 + d2];
    float2 b = *(const float2*)&hi[src_s[j + 1] * 128 + d2];
    sx += a.x + b.x; sy += a.y + b.y;
  }
  if (j < e1) {
    float2 a = *(const float2*)&hi[src_s[j] * 128 + d2];
    sx += a.x; sy += a.y;
  }
  float2 hv = *(const float2*)&hi[m * 128 + d2];
  *(float2*)&ho[m * 128 + d2] = make_float2(hv.x + sx, hv.y + sy);
}

// ---------------- shared GEMM helpers (128x128 tile, 512 threads, 4x8 per thread) ----------------
// As[r][k] stored at column k ^ ((r&7)<<2); Ws[k][c] stored at column swz(c).
__device__ __forceinline__ void stage_w(float (&Ws)[128][128], const float* __restrict__ W, int tid) {
  #pragma unroll
  for (int it = 0; it < 8; ++it) {
    int idx = (it * 512 + tid) * 4;
    int k = idx >> 7, c = idx & 127;
    *(float4*)&Ws[k][swz(c)] = *(const float4*)&W[idx];
  }
}

__device__ __forceinline__ void stage_a(float (&As)[128][128], const float* __restrict__ src,
                                        int row0, int nrows, int tid) {
  #pragma unroll
  for (int it = 0; it < 8; ++it) {
    int idx = (it * 512 + tid) * 4;
    int r = idx >> 7, k = idx & 127;
    float4 v = make_float4(0.f, 0.f, 0.f, 0.f);
    if (row0 + r < nrows) v = *(const float4*)&src[(long long)(row0 + r) * 128 + k];
    *(float4*)&As[r][k ^ ((r & 7) << 2)] = v;
  }
}

__device__ __forceinline__ void mm_accum(const float (&As)[128][128], const float (&Ws)[128][128],
                                         int rgi, int ca, int cb, float (&acc)[4][8]) {
  for (int k0 = 0; k0 < 128; k0 += 4) {
    float a_[4][4], w_[4][8];
    #pragma unroll
    for (int i = 0; i < 4; ++i) {
      int r = rgi + 32 * i;
      float4 t = *(const float4*)&As[r][k0 ^ ((r & 7) << 2)];
      a_[i][0] = t.x; a_[i][1] = t.y; a_[i][2] = t.z; a_[i][3] = t.w;
    }
    #pragma unroll
    for (int kk = 0; kk < 4; ++kk) {
      float4 w0 = *(const float4*)&Ws[k0 + kk][ca];
      float4 w1 = *(const float4*)&Ws[k0 + kk][cb];
      w_[kk][0] = w0.x; w_[kk][1] = w0.y; w_[kk][2] = w0.z; w_[kk][3] = w0.w;
      w_[kk][4] = w1.x; w_[kk][5] = w1.y; w_[kk][6] = w1.z; w_[kk][7] = w1.w;
    }
    #pragma unroll
    for (int kk = 0; kk < 4; ++kk)
      #pragma unroll
      for (int i = 0; i < 4; ++i)
        #pragma unroll
        for (int j = 0; j < 8; ++j)
          acc[i][j] = fmaf(a_[i][kk], w_[kk][j], acc[i][j]);
  }
}

__device__ __forceinline__ void bias_init(float (&acc)[4][8], const float* __restrict__ b, int c0) {
  float4 b0 = *(const float4*)&b[c0];
  float4 b1 = *(const float4*)&b[c0 + 4];
  #pragma unroll
  for (int i = 0; i < 4; ++i) {
    acc[i][0] = b0.x; acc[i][1] = b0.y; acc[i][2] = b0.z; acc[i][3] = b0.w;
    acc[i][4] = b1.x; acc[i][5] = b1.y; acc[i][6] = b1.z; acc[i][7] = b1.w;
  }
}

// out = relu( relu(h@W1 + b1) @ W2 + b2 )
__global__ __launch_bounds__(512, 2) void mlp_kernel(
    const float* __restrict__ h,
    const float* __restrict__ W1, const float* __restrict__ b1,
    const float* __restrict__ W2, const float* __restrict__ b2,
    float* __restrict__ out, int nrows) {
  __shared__ float As[128][128];
  __shared__ float Ws[128][128];
  const int tid = threadIdx.x;
  const int row0 = blockIdx.x * 128;
  stage_a(As, h, row0, nrows, tid);
  stage_w(Ws, W1, tid);
  __syncthreads();

  const int rgi = tid >> 4;      // 0..31
  const int cgi = tid & 15;      // 0..15
  const int c0 = cgi * 8;
  const int ca = swz(c0), cb = swz(c0 + 4);

  float acc[4][8];
  bias_init(acc, b1, c0);
  mm_accum(As, Ws, rgi, ca, cb, acc);
  __syncthreads();   // everyone done reading As/Ws

  // H = relu(acc) -> As (swizzled store) ; stage W2
  #pragma unroll
  for (int i = 0; i < 4; ++i) {
    int r = rgi + 32 * i;
    int o = (r & 7) << 2;
    float4 h0 = make_float4(fmaxf(acc[i][0], 0.f), fmaxf(acc[i][1], 0.f),
                            fmaxf(acc[i][2], 0.f), fmaxf(acc[i][3], 0.f));
    float4 h1 = make_float4(fmaxf(acc[i][4], 0.f), fmaxf(acc[i][5], 0.f),
                            fmaxf(acc[i][6], 0.f), fmaxf(acc[i][7], 0.f));
    *(float4*)&As[r][c0 ^ o] = h0;
    *(float4*)&As[r][(c0 + 4) ^ o] = h1;
  }
  stage_w(Ws, W2, tid);
  __syncthreads();

  float acc2[4][8];
  bias_init(acc2, b2, c0);
  mm_accum(As, Ws, rgi, ca, cb, acc2);

  #pragma unroll
  for (int i = 0; i < 4; ++i) {
    int r = row0 + rgi + 32 * i;
    if (r < nrows) {
      float4 o0 = make_float4(fmaxf(acc2[i][0], 0.f), fmaxf(acc2[i][1], 0.f),
                              fmaxf(acc2[i][2], 0.f), fmaxf(acc2[i][3], 0.f));
      float4 o1 = make_float4(fmaxf(acc2[i][4], 0.f), fmaxf(acc2[i][5], 0.f),
                              fmaxf(acc2[i][6], 0.f), fmaxf(acc2[i][7], 0.f));
      *(float4*)&out[(long long)r * 128 + c0] = o0;
      *(float4*)&out[(long long)r * 128 + c0 + 4] = o1;
    }
  }
}

// xm_nodes = relu(xcat @ lin_W + lin_b) scattered into xm_h[n2m[n]] (K=384 via 3 chunks)
__global__ __launch_bounds__(512, 2) void lin_scatter_kernel(
    const float* __restrict__ x1, const float* __restrict__ x2, const float* __restrict__ x3,
    const float* __restrict__ linW, const float* __restrict__ linb,
    const int* __restrict__ node2motif, const int* __restrict__ batch,
    const int* __restrict__ partial,
    float* __restrict__ xm_h, int nrows) {
  __shared__ float As[128][128];
  __shared__ float Ws[128][128];
  const int tid = threadIdx.x;
  const int row0 = blockIdx.x * 128;
  const int rgi = tid >> 4, cgi = tid & 15;
  const int c0 = cgi * 8;
  const int ca = swz(c0), cb = swz(c0 + 4);

  float acc[4][8];
  bias_init(acc, linb, c0);

  for (int kc = 0; kc < 3; ++kc) {
    const float* xs = (kc == 0) ? x1 : (kc == 1 ? x2 : x3);
    if (kc) __syncthreads();  // previous chunk's reads done before restage
    stage_a(As, xs, row0, nrows, tid);
    stage_w(Ws, linW + kc * 16384, tid);
    __syncthreads();
    mm_accum(As, Ws, rgi, ca, cb, acc);
  }

  #pragma unroll
  for (int i = 0; i < 4; ++i) {
    int r = row0 + rgi + 32 * i;
    if (r < nrows) {
      int m = node2motif[r] + partial[batch[r]];
      float* dp = &xm_h[m * 128 + c0];
      #pragma unroll
      for (int j = 0; j < 8; ++j) {
        float v = fmaxf(acc[i][j], 0.f);
        if (v > 0.f) atomicAdd(dp + j, v);
      }
    }
  }
}

__global__ __launch_bounds__(256) void emb_add_kernel(
    float* __restrict__ xm_h, const int* __restrict__ motifid,
    const float* __restrict__ emb, int M) {
  int t = blockIdx.x * 256 + threadIdx.x;
  int m = t >> 6;
  if (m >= M) return;
  int d2 = (t & 63) * 2;
  int id = motifid[m];
  float2 e = *(const float2*)&emb[id * 128 + d2];
  float2* p = (float2*)&xm_h[m * 128 + d2];
  float2 v = *p;
  v.x += e.x; v.y += e.y;
  *p = v;
}

// chunked node pooling: walk sorted batch[], flush partial sums at boundaries.
// 192 threads: l = tid>>6 picks layer array, lanes own float2 of dims.
__global__ __launch_bounds__(192) void xg_pool_kernel(
    const float* __restrict__ x1, const float* __restrict__ x2, const float* __restrict__ x3,
    const int* __restrict__ batch, int N, int chunk, float* __restrict__ outg) {
  const int c0 = blockIdx.x * chunk;
  if (c0 >= N) return;
  const int c1 = min(c0 + chunk, N);
  const int l = threadIdx.x >> 6;
  const int d2 = (threadIdx.x & 63) * 2;
  const float* xs = (l == 0) ? x1 : (l == 1 ? x2 : x3);
  int b = batch[c0];
  float sx = 0.f, sy = 0.f;
  for (int n = c0; n < c1; ++n) {
    int bn = batch[n];
    if (bn != b) {
      if (sx != 0.f) atomicAdd(&outg[b * 384 + l * 128 + d2], sx);
      if (sy != 0.f) atomicAdd(&outg[b * 384 + l * 128 + d2 + 1], sy);
      sx = 0.f; sy = 0.f; b = bn;
    }
    float2 v = *(const float2*)&xs[n * 128 + d2];
    sx += v.x; sy += v.y;
  }
  atomicAdd(&outg[b * 384 + l * 128 + d2], sx);
  atomicAdd(&outg[b * 384 + l * 128 + d2 + 1], sy);
}

// chunked motif pooling; motif->batch via partial[] walk (motifs contiguous per batch)
__global__ __launch_bounds__(128) void xm_pool_kernel(
    const float* __restrict__ m1, const float* __restrict__ m2,
    const int* __restrict__ partial, int B, int M, int chunk,
    float* __restrict__ outm) {
  const int c0 = blockIdx.x * chunk;
  if (c0 >= M) return;
  const int c1 = min(c0 + chunk, M);
  const int l = threadIdx.x >> 6;
  const int d2 = (threadIdx.x & 63) * 2;
  const float* ms = (l == 0) ? m1 : m2;
  int b = 0;
  while (b + 1 < B && partial[b + 1] <= c0) ++b;
  int bend = (b + 1 < B) ? partial[b + 1] : M;
  float sx = 0.f, sy = 0.f;
  for (int m = c0; m < c1; ++m) {
    if (m >= bend) {
      if (sx != 0.f) atomicAdd(&outm[b * 256 + l * 128 + d2], sx);
      if (sy != 0.f) atomicAdd(&outm[b * 256 + l * 128 + d2 + 1], sy);
      sx = 0.f; sy = 0.f;
      do { ++b; } while (b + 1 < B && partial[b + 1] <= m);
      bend = (b + 1 < B) ? partial[b + 1] : M;
    }
    float2 v = *(const float2*)&ms[m * 128 + d2];
    sx += v.x; sy += v.y;
  }
  atomicAdd(&outm[b * 256 + l * 128 + d2], sx);
  atomicAdd(&outm[b * 256 + l * 128 + d2 + 1], sy);
}

extern "C" void kernel_launch(void* const* d_in, const int* in_sizes, int n_in,
                              void* d_out, int out_size, void* d_ws, size_t ws_size,
                              hipStream_t stream) {
  const float* x       = (const float*)d_in[0];
  const float* ea      = (const float*)d_in[1];
  const int*   eidx    = (const int*)d_in[2];
  const int*   batch   = (const int*)d_in[3];
  const int*   n2m     = (const int*)d_in[4];
  const int*   nmot    = (const int*)d_in[5];
  const int*   meidx   = (const int*)d_in[6];
  const int*   motifid = (const int*)d_in[7];
  const float* gcW1 = (const float*)d_in[8];
  const float* gcb1 = (const float*)d_in[9];
  const float* gcW2 = (const float*)d_in[10];
  const float* gcb2 = (const float*)d_in[11];
  const float* mcW1 = (const float*)d_in[12];
  const float* mcb1 = (const float*)d_in[13];
  const float* mcW2 = (const float*)d_in[14];
  const float* mcb2 = (const float*)d_in[15];
  const float* linW = (const float*)d_in[16];
  const float* linb = (const float*)d_in[17];
  const float* emb  = (const float*)d_in[18];
  float* outp = (float*)d_out;

  const int N  = in_sizes[0] / 128;   // 50000
  const int E  = in_sizes[1] / 128;   // 600000
  const int B  = in_sizes[5];         // 64
  const int ME = in_sizes[6] / 2;     // 50000
  const int M  = in_sizes[7];         // 6400

  const size_t nodeBytes = (size_t)N * 128 * 4;     // 25.6 MB
  const size_t motBytes  = (size_t)M * 128 * 4;     // 3.28 MB
  char* ws = (char*)d_ws;
  float* xl0 = (float*)ws;                 ws += nodeBytes;
  float* xl1 = (float*)ws;                 ws += nodeBytes;
  float* xl2 = (float*)ws;                 ws += nodeBytes;
  char*  R   = ws;                         ws += nodeBytes;   // h during GINE; motif bufs after
  int* counts  = (int*)ws;                 ws += (size_t)N * 4;
  int* base    = (int*)ws;                 ws += (size_t)(N + 1) * 4;
  int* cursor  = (int*)ws;                 ws += (size_t)N * 4;
  int* eid_s   = (int*)ws;                 ws += (size_t)E * 4;
  int* src_s   = (int*)ws;                 ws += (size_t)E * 4;
  int* mcounts = (int*)ws;                 ws += (size_t)M * 4;
  int* mbase   = (int*)ws;                 ws += (size_t)(M + 1) * 4;
  int* mcursor = (int*)ws;                 ws += (size_t)M * 4;
  int* meid_s  = (int*)ws;                 ws += (size_t)ME * 4;
  int* msrc_s  = (int*)ws;                 ws += (size_t)ME * 4;
  int* partial = (int*)ws;                 ws += 256;
  int* bnd     = (int*)ws;                 ws += 512;
  if ((size_t)(ws - (char*)d_ws) > ws_size) return;  // ws too small

  float* hbuf = (float*)R;                 // GINE h = x + agg
  float* xmh  = (float*)R;                 // motif h0 (reused after GINE stage)
  float* hm   = (float*)(R + motBytes);    // motif h+agg temp
  float* ml0  = (float*)(R + 2 * motBytes);
  float* ml1  = (float*)(R + 3 * motBytes);

  // d_out is poisoned: zero it (pool kernels accumulate via atomics)
  hipMemsetAsync(outp, 0, (size_t)out_size * 4, stream);

  prep_kernel<<<1, 128, 0, stream>>>(nmot, batch, N, B, partial, bnd);

  // ---- build node-graph CSR by dst ----
  const int* src = eidx;
  const int* dst = eidx + E;
  hipMemsetAsync(counts, 0, (size_t)N * 4, stream);
  hist_kernel<<<(E + 255) / 256, 256, 0, stream>>>(dst, E, counts);
  scan_kernel<<<1, 1024, 0, stream>>>(counts, N, base, cursor);
  scatter_kernel<<<(E + 255) / 256, 256, 0, stream>>>(src, dst, E, cursor, eid_s, src_s);

  // ---- build motif-graph CSR by dst ----
  const int* msrc = meidx;
  const int* mdst = meidx + ME;
  hipMemsetAsync(mcounts, 0, (size_t)M * 4, stream);
  hist_kernel<<<(ME + 255) / 256, 256, 0, stream>>>(mdst, ME, mcounts);
  scan_kernel<<<1, 1024, 0, stream>>>(mcounts, M, mbase, mcursor);
  scatter_kernel<<<(ME + 255) / 256, 256, 0, stream>>>(msrc, mdst, ME, mcursor, meid_s, msrc_s);

  // ---- GINE stack ----
  const float* xs[3] = {x, xl0, xl1};
  float* xo[3] = {xl0, xl1, xl2};
  const int ngrid = (N + 127) / 128;
  for (int i = 0; i < 3; ++i) {
    gine_agg_kernel<<<(N + 1) / 2, 128, 0, stream>>>(xs[i], ea, base, eid_s, src_s, hbuf, N);
    mlp_kernel<<<ngrid, 512, 0, stream>>>(hbuf,
        gcW1 + (size_t)i * 16384, gcb1 + i * 128,
        gcW2 + (size_t)i * 16384, gcb2 + i * 128, xo[i], N);
  }
  {
    const int nb = 256;
    const int chunk = (N + nb - 1) / nb;
    xg_pool_kernel<<<nb, 192, 0, stream>>>(xl0, xl1, xl2, batch, N, chunk, outp + B * 256);
  }

  // ---- motif features ----
  hipMemsetAsync(xmh, 0, motBytes, stream);
  lin_scatter_kernel<<<ngrid, 512, 0, stream>>>(xl0, xl1, xl2, linW, linb,
      n2m, batch, partial, xmh, N);
  emb_add_kernel<<<(M * 64 + 255) / 256, 256, 0, stream>>>(xmh, motifid, emb, M);

  // ---- motif GIN stack ----
  const float* hs[2] = {xmh, ml0};
  float* mo[2] = {ml0, ml1};
  const int mgrid = (M + 127) / 128;
  for (int i = 0; i < 2; ++i) {
    gin_agg_kernel<<<(M + 1) / 2, 128, 0, stream>>>(hs[i], mbase, msrc_s, hm, M);
    mlp_kernel<<<mgrid, 512, 0, stream>>>(hm,
        mcW1 + (size_t)i * 16384, mcb1 + i * 128,
        mcW2 + (size_t)i * 16384, mcb2 + i * 128, mo[i], M);
  }
  {
    const int nb = 128;
    const int chunk = (M + nb - 1) / nb;
    xm_pool_kernel<<<nb, 128, 0, stream>>>(ml0, ml1, partial, B, M, chunk, outp);
  }
}

// Round 4
// 1364.709 us; speedup vs baseline: 1.0577x; 1.0577x over previous
//
#include <hip/hip_runtime.h>

__device__ __forceinline__ int swz(int c) { return c ^ (((c >> 5) & 3) << 2); }

// ---------------- prep: motif prefix offsets + batch boundaries ----------------
__global__ void prep_kernel(const int* __restrict__ num_motifs,
                            const int* __restrict__ batch,
                            int N, int B,
                            int* __restrict__ partial,
                            int* __restrict__ bnd) {
  int t = threadIdx.x;
  if (t == 0) {
    int s = 0;
    for (int b = 0; b < B; ++b) { partial[b] = s; s += num_motifs[b]; }
  }
  if (t <= B) {  // lower_bound(batch, t) over sorted batch
    int lo = 0, hi = N;
    while (lo < hi) { int mid = (lo + hi) >> 1; if (batch[mid] < t) lo = mid + 1; else hi = mid; }
    bnd[t] = lo;
  }
}

// ---------------- CSR build: histogram -> scan -> scatter ----------------
__global__ __launch_bounds__(256) void hist_kernel(const int* __restrict__ dst, int E,
                                                   int* __restrict__ counts) {
  int e = blockIdx.x * 256 + threadIdx.x;
  if (e < E) atomicAdd(&counts[dst[e]], 1);
}

// single block, 1024 threads: exclusive scan counts[0..n) -> base[0..n], cursor=base copy
__global__ __launch_bounds__(1024) void scan_kernel(const int* __restrict__ counts, int n,
                                                    int* __restrict__ base,
                                                    int* __restrict__ cursor) {
  __shared__ int part[1024];
  const int tid = threadIdx.x;
  const int chunk = (n + 1023) / 1024;
  const int lo = tid * chunk;
  const int hi = min(lo + chunk, n);
  int s = 0;
  for (int i = lo; i < hi; ++i) s += counts[i];
  part[tid] = s;
  __syncthreads();
  for (int off = 1; off < 1024; off <<= 1) {
    int v = (tid >= off) ? part[tid - off] : 0;
    __syncthreads();
    part[tid] += v;
    __syncthreads();
  }
  int run = (tid > 0) ? part[tid - 1] : 0;   // exclusive prefix of this chunk
  for (int i = lo; i < hi; ++i) {
    base[i] = run; cursor[i] = run;
    run += counts[i];
  }
  if (tid == 1023) base[n] = part[1023];
}

__global__ __launch_bounds__(256) void scatter_kernel(const int* __restrict__ src,
                                                      const int* __restrict__ dst, int E,
                                                      int* __restrict__ cursor,
                                                      int* __restrict__ eid_s,
                                                      int* __restrict__ src_s) {
  int e = blockIdx.x * 256 + threadIdx.x;
  if (e >= E) return;
  int d = dst[e];
  int pos = atomicAdd(&cursor[d], 1);
  eid_s[pos] = e;
  src_s[pos] = src[e];
}

// node -> motif CSR (key computed on the fly: n2m[n] + partial[batch[n]])
__global__ __launch_bounds__(256) void nm_hist_kernel(const int* __restrict__ n2m,
                                                      const int* __restrict__ batch,
                                                      const int* __restrict__ partial, int N,
                                                      int* __restrict__ counts) {
  int n = blockIdx.x * 256 + threadIdx.x;
  if (n < N) atomicAdd(&counts[n2m[n] + partial[batch[n]]], 1);
}

__global__ __launch_bounds__(256) void nm_scatter_kernel(const int* __restrict__ n2m,
                                                         const int* __restrict__ batch,
                                                         const int* __restrict__ partial, int N,
                                                         int* __restrict__ cursor,
                                                         int* __restrict__ node_s) {
  int n = blockIdx.x * 256 + threadIdx.x;
  if (n >= N) return;
  int m = n2m[n] + partial[batch[n]];
  node_s[atomicAdd(&cursor[m], 1)] = n;
}

// ---- GINE pull-aggregate fused with self: h[n,d] = x[n,d] + sum_e relu(x[src_e,d]+ea[e,d]) ----
__global__ __launch_bounds__(128) void gine_agg_kernel(
    const float* __restrict__ x, const float* __restrict__ ea,
    const int* __restrict__ base, const int* __restrict__ eid_s,
    const int* __restrict__ src_s, float* __restrict__ h, int N) {
  const int n = blockIdx.x * 2 + (threadIdx.x >> 6);
  if (n >= N) return;
  const int d2 = (threadIdx.x & 63) * 2;
  const int e0 = base[n], e1 = base[n + 1];
  float sx = 0.f, sy = 0.f;
  int j = e0;
  for (; j + 1 < e1; j += 2) {
    int eA = eid_s[j],     sA = src_s[j];
    int eB = eid_s[j + 1], sB = src_s[j + 1];
    float2 xa = *(const float2*)&x[sA * 128 + d2];
    float2 ja = *(const float2*)&ea[(long long)eA * 128 + d2];
    float2 xb = *(const float2*)&x[sB * 128 + d2];
    float2 jb = *(const float2*)&ea[(long long)eB * 128 + d2];
    sx += fmaxf(xa.x + ja.x, 0.f) + fmaxf(xb.x + jb.x, 0.f);
    sy += fmaxf(xa.y + ja.y, 0.f) + fmaxf(xb.y + jb.y, 0.f);
  }
  if (j < e1) {
    float2 xa = *(const float2*)&x[src_s[j] * 128 + d2];
    float2 ja = *(const float2*)&ea[(long long)eid_s[j] * 128 + d2];
    sx += fmaxf(xa.x + ja.x, 0.f);
    sy += fmaxf(xa.y + ja.y, 0.f);
  }
  float2 xv = *(const float2*)&x[n * 128 + d2];
  *(float2*)&h[n * 128 + d2] = make_float2(xv.x + sx, xv.y + sy);
}

// ---- GIN pull-aggregate fused with self: ho[m,d] = hi[m,d] + sum_e hi[src_e,d] ----
__global__ __launch_bounds__(128) void gin_agg_kernel(
    const float* __restrict__ hi, const int* __restrict__ base,
    const int* __restrict__ src_s, float* __restrict__ ho, int M) {
  const int m = blockIdx.x * 2 + (threadIdx.x >> 6);
  if (m >= M) return;
  const int d2 = (threadIdx.x & 63) * 2;
  const int e0 = base[m], e1 = base[m + 1];
  float sx = 0.f, sy = 0.f;
  int j = e0;
  for (; j + 1 < e1; j += 2) {
    float2 a = *(const float2*)&hi[src_s[j] * 128 + d2];
    float2 b = *(const float2*)&hi[src_s[j + 1] * 128 + d2];
    sx += a.x + b.x; sy += a.y + b.y;
  }
  if (j < e1) {
    float2 a = *(const float2*)&hi[src_s[j] * 128 + d2];
    sx += a.x; sy += a.y;
  }
  float2 hv = *(const float2*)&hi[m * 128 + d2];
  *(float2*)&ho[m * 128 + d2] = make_float2(hv.x + sx, hv.y + sy);
}

// ---- motif gather: xm_h[m,d] = emb[motifid[m],d] + sum_{nodes in m} xm_nodes[node,d] ----
__global__ __launch_bounds__(128) void motif_gather_kernel(
    const float* __restrict__ xm_nodes, const int* __restrict__ mb,
    const int* __restrict__ node_s, const int* __restrict__ motifid,
    const float* __restrict__ emb, float* __restrict__ xm_h, int M) {
  const int m = blockIdx.x * 2 + (threadIdx.x >> 6);
  if (m >= M) return;
  const int d2 = (threadIdx.x & 63) * 2;
  float2 e = *(const float2*)&emb[motifid[m] * 128 + d2];
  float sx = e.x, sy = e.y;
  const int j0 = mb[m], j1 = mb[m + 1];
  int j = j0;
  for (; j + 1 < j1; j += 2) {
    float2 a = *(const float2*)&xm_nodes[(long long)node_s[j] * 128 + d2];
    float2 b = *(const float2*)&xm_nodes[(long long)node_s[j + 1] * 128 + d2];
    sx += a.x + b.x; sy += a.y + b.y;
  }
  if (j < j1) {
    float2 a = *(const float2*)&xm_nodes[(long long)node_s[j] * 128 + d2];
    sx += a.x; sy += a.y;
  }
  *(float2*)&xm_h[m * 128 + d2] = make_float2(sx, sy);
}

// ---------------- GEMM helpers: 128x128 tile, 256 threads, 8x8 per thread ----------------
// As[r][k] stored at column k ^ ((r&7)<<2); Ws[k][c] stored at column swz(c).
__device__ __forceinline__ void stage_w(float (&Ws)[128][128], const float* __restrict__ W, int tid) {
  #pragma unroll
  for (int it = 0; it < 16; ++it) {
    int idx = (it * 256 + tid) * 4;
    int k = idx >> 7, c = idx & 127;
    *(float4*)&Ws[k][swz(c)] = *(const float4*)&W[idx];
  }
}

__device__ __forceinline__ void stage_a(float (&As)[128][128], const float* __restrict__ src,
                                        int row0, int nrows, int tid) {
  #pragma unroll
  for (int it = 0; it < 16; ++it) {
    int idx = (it * 256 + tid) * 4;
    int r = idx >> 7, k = idx & 127;
    float4 v = make_float4(0.f, 0.f, 0.f, 0.f);
    if (row0 + r < nrows) v = *(const float4*)&src[(long long)(row0 + r) * 128 + k];
    *(float4*)&As[r][k ^ ((r & 7) << 2)] = v;
  }
}

__device__ __forceinline__ void mm_accum(const float (&As)[128][128], const float (&Ws)[128][128],
                                         int rgi, int ca, int cb, float (&acc)[8][8]) {
  for (int k0 = 0; k0 < 128; k0 += 4) {
    float a_[8][4], w_[4][8];
    #pragma unroll
    for (int i = 0; i < 8; ++i) {
      int r = rgi + 16 * i;
      float4 t = *(const float4*)&As[r][k0 ^ ((r & 7) << 2)];
      a_[i][0] = t.x; a_[i][1] = t.y; a_[i][2] = t.z; a_[i][3] = t.w;
    }
    #pragma unroll
    for (int kk = 0; kk < 4; ++kk) {
      float4 w0 = *(const float4*)&Ws[k0 + kk][ca];
      float4 w1 = *(const float4*)&Ws[k0 + kk][cb];
      w_[kk][0] = w0.x; w_[kk][1] = w0.y; w_[kk][2] = w0.z; w_[kk][3] = w0.w;
      w_[kk][4] = w1.x; w_[kk][5] = w1.y; w_[kk][6] = w1.z; w_[kk][7] = w1.w;
    }
    #pragma unroll
    for (int kk = 0; kk < 4; ++kk)
      #pragma unroll
      for (int i = 0; i < 8; ++i)
        #pragma unroll
        for (int j = 0; j < 8; ++j)
          acc[i][j] = fmaf(a_[i][kk], w_[kk][j], acc[i][j]);
  }
}

__device__ __forceinline__ void bias_init(float (&acc)[8][8], const float* __restrict__ b, int c0) {
  float4 b0 = *(const float4*)&b[c0];
  float4 b1 = *(const float4*)&b[c0 + 4];
  #pragma unroll
  for (int i = 0; i < 8; ++i) {
    acc[i][0] = b0.x; acc[i][1] = b0.y; acc[i][2] = b0.z; acc[i][3] = b0.w;
    acc[i][4] = b1.x; acc[i][5] = b1.y; acc[i][6] = b1.z; acc[i][7] = b1.w;
  }
}

// out = relu( relu(h@W1 + b1) @ W2 + b2 )
__global__ __launch_bounds__(256, 1) void mlp_kernel(
    const float* __restrict__ h,
    const float* __restrict__ W1, const float* __restrict__ b1,
    const float* __restrict__ W2, const float* __restrict__ b2,
    float* __restrict__ out, int nrows) {
  __shared__ float As[128][128];
  __shared__ float Ws[128][128];
  const int tid = threadIdx.x;
  const int row0 = blockIdx.x * 128;
  stage_a(As, h, row0, nrows, tid);
  stage_w(Ws, W1, tid);
  __syncthreads();

  const int rgi = tid >> 4;      // 0..15, rows rgi + 16*i
  const int cgi = tid & 15;      // 0..15
  const int c0 = cgi * 8;
  const int ca = swz(c0), cb = swz(c0 + 4);

  float acc[8][8];
  bias_init(acc, b1, c0);
  mm_accum(As, Ws, rgi, ca, cb, acc);
  __syncthreads();   // everyone done reading As/Ws

  // H = relu(acc) -> As (swizzled store) ; stage W2
  #pragma unroll
  for (int i = 0; i < 8; ++i) {
    int r = rgi + 16 * i;
    int o = (r & 7) << 2;
    float4 h0 = make_float4(fmaxf(acc[i][0], 0.f), fmaxf(acc[i][1], 0.f),
                            fmaxf(acc[i][2], 0.f), fmaxf(acc[i][3], 0.f));
    float4 h1 = make_float4(fmaxf(acc[i][4], 0.f), fmaxf(acc[i][5], 0.f),
                            fmaxf(acc[i][6], 0.f), fmaxf(acc[i][7], 0.f));
    *(float4*)&As[r][c0 ^ o] = h0;
    *(float4*)&As[r][(c0 + 4) ^ o] = h1;
  }
  stage_w(Ws, W2, tid);
  __syncthreads();

  float acc2[8][8];
  bias_init(acc2, b2, c0);
  mm_accum(As, Ws, rgi, ca, cb, acc2);

  #pragma unroll
  for (int i = 0; i < 8; ++i) {
    int r = row0 + rgi + 16 * i;
    if (r < nrows) {
      float4 o0 = make_float4(fmaxf(acc2[i][0], 0.f), fmaxf(acc2[i][1], 0.f),
                              fmaxf(acc2[i][2], 0.f), fmaxf(acc2[i][3], 0.f));
      float4 o1 = make_float4(fmaxf(acc2[i][4], 0.f), fmaxf(acc2[i][5], 0.f),
                              fmaxf(acc2[i][6], 0.f), fmaxf(acc2[i][7], 0.f));
      *(float4*)&out[(long long)r * 128 + c0] = o0;
      *(float4*)&out[(long long)r * 128 + c0 + 4] = o1;
    }
  }
}

// xm_nodes = relu(xcat @ lin_W + lin_b)  (K=384 via 3 chunks) — plain store, no atomics
__global__ __launch_bounds__(256, 1) void lin_kernel(
    const float* __restrict__ x1, const float* __restrict__ x2, const float* __restrict__ x3,
    const float* __restrict__ linW, const float* __restrict__ linb,
    float* __restrict__ xm_nodes, int nrows) {
  __shared__ float As[128][128];
  __shared__ float Ws[128][128];
  const int tid = threadIdx.x;
  const int row0 = blockIdx.x * 128;
  const int rgi = tid >> 4, cgi = tid & 15;
  const int c0 = cgi * 8;
  const int ca = swz(c0), cb = swz(c0 + 4);

  float acc[8][8];
  bias_init(acc, linb, c0);

  for (int kc = 0; kc < 3; ++kc) {
    const float* xs = (kc == 0) ? x1 : (kc == 1 ? x2 : x3);
    if (kc) __syncthreads();  // previous chunk's reads done before restage
    stage_a(As, xs, row0, nrows, tid);
    stage_w(Ws, linW + kc * 16384, tid);
    __syncthreads();
    mm_accum(As, Ws, rgi, ca, cb, acc);
  }

  #pragma unroll
  for (int i = 0; i < 8; ++i) {
    int r = row0 + rgi + 16 * i;
    if (r < nrows) {
      float4 o0 = make_float4(fmaxf(acc[i][0], 0.f), fmaxf(acc[i][1], 0.f),
                              fmaxf(acc[i][2], 0.f), fmaxf(acc[i][3], 0.f));
      float4 o1 = make_float4(fmaxf(acc[i][4], 0.f), fmaxf(acc[i][5], 0.f),
                              fmaxf(acc[i][6], 0.f), fmaxf(acc[i][7], 0.f));
      *(float4*)&xm_nodes[(long long)r * 128 + c0] = o0;
      *(float4*)&xm_nodes[(long long)r * 128 + c0 + 4] = o1;
    }
  }
}

// chunked node pooling: walk sorted batch[], flush partial sums at boundaries.
__global__ __launch_bounds__(192) void xg_pool_kernel(
    const float* __restrict__ x1, const float* __restrict__ x2, const float* __restrict__ x3,
    const int* __restrict__ batch, int N, int chunk, float* __restrict__ outg) {
  const int c0 = blockIdx.x * chunk;
  if (c0 >= N) return;
  const int c1 = min(c0 + chunk, N);
  const int l = threadIdx.x >> 6;
  const int d2 = (threadIdx.x & 63) * 2;
  const float* xs = (l == 0) ? x1 : (l == 1 ? x2 : x3);
  int b = batch[c0];
  float sx = 0.f, sy = 0.f;
  for (int n = c0; n < c1; ++n) {
    int bn = batch[n];
    if (bn != b) {
      if (sx != 0.f) atomicAdd(&outg[b * 384 + l * 128 + d2], sx);
      if (sy != 0.f) atomicAdd(&outg[b * 384 + l * 128 + d2 + 1], sy);
      sx = 0.f; sy = 0.f; b = bn;
    }
    float2 v = *(const float2*)&xs[n * 128 + d2];
    sx += v.x; sy += v.y;
  }
  atomicAdd(&outg[b * 384 + l * 128 + d2], sx);
  atomicAdd(&outg[b * 384 + l * 128 + d2 + 1], sy);
}

// chunked motif pooling; motif->batch via partial[] walk (motifs contiguous per batch)
__global__ __launch_bounds__(128) void xm_pool_kernel(
    const float* __restrict__ m1, const float* __restrict__ m2,
    const int* __restrict__ partial, int B, int M, int chunk,
    float* __restrict__ outm) {
  const int c0 = blockIdx.x * chunk;
  if (c0 >= M) return;
  const int c1 = min(c0 + chunk, M);
  const int l = threadIdx.x >> 6;
  const int d2 = (threadIdx.x & 63) * 2;
  const float* ms = (l == 0) ? m1 : m2;
  int b = 0;
  while (b + 1 < B && partial[b + 1] <= c0) ++b;
  int bend = (b + 1 < B) ? partial[b + 1] : M;
  float sx = 0.f, sy = 0.f;
  for (int m = c0; m < c1; ++m) {
    if (m >= bend) {
      if (sx != 0.f) atomicAdd(&outm[b * 256 + l * 128 + d2], sx);
      if (sy != 0.f) atomicAdd(&outm[b * 256 + l * 128 + d2 + 1], sy);
      sx = 0.f; sy = 0.f;
      do { ++b; } while (b + 1 < B && partial[b + 1] <= m);
      bend = (b + 1 < B) ? partial[b + 1] : M;
    }
    float2 v = *(const float2*)&ms[m * 128 + d2];
    sx += v.x; sy += v.y;
  }
  atomicAdd(&outm[b * 256 + l * 128 + d2], sx);
  atomicAdd(&outm[b * 256 + l * 128 + d2 + 1], sy);
}

extern "C" void kernel_launch(void* const* d_in, const int* in_sizes, int n_in,
                              void* d_out, int out_size, void* d_ws, size_t ws_size,
                              hipStream_t stream) {
  const float* x       = (const float*)d_in[0];
  const float* ea      = (const float*)d_in[1];
  const int*   eidx    = (const int*)d_in[2];
  const int*   batch   = (const int*)d_in[3];
  const int*   n2m     = (const int*)d_in[4];
  const int*   nmot    = (const int*)d_in[5];
  const int*   meidx   = (const int*)d_in[6];
  const int*   motifid = (const int*)d_in[7];
  const float* gcW1 = (const float*)d_in[8];
  const float* gcb1 = (const float*)d_in[9];
  const float* gcW2 = (const float*)d_in[10];
  const float* gcb2 = (const float*)d_in[11];
  const float* mcW1 = (const float*)d_in[12];
  const float* mcb1 = (const float*)d_in[13];
  const float* mcW2 = (const float*)d_in[14];
  const float* mcb2 = (const float*)d_in[15];
  const float* linW = (const float*)d_in[16];
  const float* linb = (const float*)d_in[17];
  const float* emb  = (const float*)d_in[18];
  float* outp = (float*)d_out;

  const int N  = in_sizes[0] / 128;   // 50000
  const int E  = in_sizes[1] / 128;   // 600000
  const int B  = in_sizes[5];         // 64
  const int ME = in_sizes[6] / 2;     // 50000
  const int M  = in_sizes[7];         // 6400

  const size_t nodeBytes = (size_t)N * 128 * 4;     // 25.6 MB
  const size_t motBytes  = (size_t)M * 128 * 4;     // 3.28 MB
  char* ws = (char*)d_ws;
  float* xl0 = (float*)ws;                 ws += nodeBytes;
  float* xl1 = (float*)ws;                 ws += nodeBytes;
  float* xl2 = (float*)ws;                 ws += nodeBytes;
  char*  R   = ws;                         ws += nodeBytes;   // h during GINE; xm_nodes after
  int* counts  = (int*)ws;                 ws += (size_t)N * 4;
  int* base    = (int*)ws;                 ws += (size_t)(N + 1) * 4;
  int* cursor  = (int*)ws;                 ws += (size_t)N * 4;
  int* eid_s   = (int*)ws;                 ws += (size_t)E * 4;
  int* src_s   = (int*)ws;                 ws += (size_t)E * 4;
  int* mcounts = (int*)ws;                 ws += (size_t)M * 4;
  int* mbase   = (int*)ws;                 ws += (size_t)(M + 1) * 4;
  int* mcursor = (int*)ws;                 ws += (size_t)M * 4;
  int* meid_s  = (int*)ws;                 ws += (size_t)ME * 4;
  int* msrc_s  = (int*)ws;                 ws += (size_t)ME * 4;
  int* nmcnt   = (int*)ws;                 ws += (size_t)M * 4;
  int* nmbase  = (int*)ws;                 ws += (size_t)(M + 1) * 4;
  int* nmcur   = (int*)ws;                 ws += (size_t)M * 4;
  int* node_s  = (int*)ws;                 ws += (size_t)N * 4;
  int* partial = (int*)ws;                 ws += 256;
  int* bnd     = (int*)ws;                 ws += 512;
  if ((size_t)(ws - (char*)d_ws) > ws_size) return;  // ws too small

  float* hbuf     = (float*)R;             // GINE h = x + agg (transient per layer)
  float* xm_nodes = (float*)R;             // relu(lin(xcat)) after GINE stage
  // motif buffers live in xl0's region (xl0..2 are dead after lin_kernel)
  float* xmh = (float*)((char*)xl0);
  float* hm  = (float*)((char*)xl0 + motBytes);
  float* ml0 = (float*)((char*)xl0 + 2 * motBytes);
  float* ml1 = (float*)((char*)xl0 + 3 * motBytes);

  // d_out is poisoned: zero it (pool kernels accumulate via atomics)
  hipMemsetAsync(outp, 0, (size_t)out_size * 4, stream);

  prep_kernel<<<1, 128, 0, stream>>>(nmot, batch, N, B, partial, bnd);

  // ---- build node-graph CSR by dst ----
  const int* src = eidx;
  const int* dst = eidx + E;
  hipMemsetAsync(counts, 0, (size_t)N * 4, stream);
  hist_kernel<<<(E + 255) / 256, 256, 0, stream>>>(dst, E, counts);
  scan_kernel<<<1, 1024, 0, stream>>>(counts, N, base, cursor);
  scatter_kernel<<<(E + 255) / 256, 256, 0, stream>>>(src, dst, E, cursor, eid_s, src_s);

  // ---- build motif-graph CSR by dst ----
  const int* msrc = meidx;
  const int* mdst = meidx + ME;
  hipMemsetAsync(mcounts, 0, (size_t)M * 4, stream);
  hist_kernel<<<(ME + 255) / 256, 256, 0, stream>>>(mdst, ME, mcounts);
  scan_kernel<<<1, 1024, 0, stream>>>(mcounts, M, mbase, mcursor);
  scatter_kernel<<<(ME + 255) / 256, 256, 0, stream>>>(msrc, mdst, ME, mcursor, meid_s, msrc_s);

  // ---- build node->motif CSR (needs partial from prep; stream-ordered) ----
  hipMemsetAsync(nmcnt, 0, (size_t)M * 4, stream);
  nm_hist_kernel<<<(N + 255) / 256, 256, 0, stream>>>(n2m, batch, partial, N, nmcnt);
  scan_kernel<<<1, 1024, 0, stream>>>(nmcnt, M, nmbase, nmcur);
  nm_scatter_kernel<<<(N + 255) / 256, 256, 0, stream>>>(n2m, batch, partial, N, nmcur, node_s);

  // ---- GINE stack ----
  const float* xs[3] = {x, xl0, xl1};
  float* xo[3] = {xl0, xl1, xl2};
  const int ngrid = (N + 127) / 128;
  for (int i = 0; i < 3; ++i) {
    gine_agg_kernel<<<(N + 1) / 2, 128, 0, stream>>>(xs[i], ea, base, eid_s, src_s, hbuf, N);
    mlp_kernel<<<ngrid, 256, 0, stream>>>(hbuf,
        gcW1 + (size_t)i * 16384, gcb1 + i * 128,
        gcW2 + (size_t)i * 16384, gcb2 + i * 128, xo[i], N);
  }
  {
    const int nb = 512;
    const int chunk = (N + nb - 1) / nb;
    xg_pool_kernel<<<nb, 192, 0, stream>>>(xl0, xl1, xl2, batch, N, chunk, outp + B * 256);
  }

  // ---- motif features: lin (no atomics) then CSR gather (+emb fused) ----
  lin_kernel<<<ngrid, 256, 0, stream>>>(xl0, xl1, xl2, linW, linb, xm_nodes, N);
  motif_gather_kernel<<<(M + 1) / 2, 128, 0, stream>>>(xm_nodes, nmbase, node_s,
                                                       motifid, emb, xmh, M);

  // ---- motif GIN stack ----
  const float* hs[2] = {xmh, ml0};
  float* mo[2] = {ml0, ml1};
  const int mgrid = (M + 127) / 128;
  for (int i = 0; i < 2; ++i) {
    gin_agg_kernel<<<(M + 1) / 2, 128, 0, stream>>>(hs[i], mbase, msrc_s, hm, M);
    mlp_kernel<<<mgrid, 256, 0, stream>>>(hm,
        mcW1 + (size_t)i * 16384, mcb1 + i * 128,
        mcW2 + (size_t)i * 16384, mcb2 + i * 128, mo[i], M);
  }
  {
    const int nb = 256;
    const int chunk = (M + nb - 1) / nb;
    xm_pool_kernel<<<nb, 128, 0, stream>>>(ml0, ml1, partial, B, M, chunk, outp);
  }
}

// Round 5
// 1125.439 us; speedup vs baseline: 1.2825x; 1.2126x over previous
//
#include <hip/hip_runtime.h>

typedef __attribute__((ext_vector_type(8))) short bf16x8;
typedef __attribute__((ext_vector_type(4))) float f32x4;

// ---------------- bf16 split helpers ----------------
__device__ __forceinline__ unsigned f2bf_rne(float f) {
  unsigned u = __float_as_uint(f);
  return (u + 0x7FFFu + ((u >> 16) & 1u)) >> 16;
}
__device__ __forceinline__ float bf2f(unsigned h) { return __uint_as_float(h << 16); }
__device__ __forceinline__ void split_bf(float x, unsigned& hi, unsigned& lo) {
  hi = f2bf_rne(x);
  lo = f2bf_rne(x - bf2f(hi));
}

// ---------------- prep: motif prefix offsets + batch boundaries ----------------
__global__ void prep_kernel(const int* __restrict__ num_motifs,
                            const int* __restrict__ batch,
                            int N, int B,
                            int* __restrict__ partial,
                            int* __restrict__ bnd) {
  int t = threadIdx.x;
  if (t == 0) {
    int s = 0;
    for (int b = 0; b < B; ++b) { partial[b] = s; s += num_motifs[b]; }
  }
  if (t <= B) {
    int lo = 0, hi = N;
    while (lo < hi) { int mid = (lo + hi) >> 1; if (batch[mid] < t) lo = mid + 1; else hi = mid; }
    bnd[t] = lo;
  }
}

// ---------------- CSR build ----------------
__global__ __launch_bounds__(256) void hist_kernel(const int* __restrict__ dst, int E,
                                                   int* __restrict__ counts) {
  int e = blockIdx.x * 256 + threadIdx.x;
  if (e < E) atomicAdd(&counts[dst[e]], 1);
}

__global__ __launch_bounds__(1024) void scan_kernel(const int* __restrict__ counts, int n,
                                                    int* __restrict__ base,
                                                    int* __restrict__ cursor) {
  __shared__ int part[1024];
  const int tid = threadIdx.x;
  const int chunk = (n + 1023) / 1024;
  const int lo = tid * chunk;
  const int hi = min(lo + chunk, n);
  int s = 0;
  for (int i = lo; i < hi; ++i) s += counts[i];
  part[tid] = s;
  __syncthreads();
  for (int off = 1; off < 1024; off <<= 1) {
    int v = (tid >= off) ? part[tid - off] : 0;
    __syncthreads();
    part[tid] += v;
    __syncthreads();
  }
  int run = (tid > 0) ? part[tid - 1] : 0;
  for (int i = lo; i < hi; ++i) {
    base[i] = run; cursor[i] = run;
    run += counts[i];
  }
  if (tid == 1023) base[n] = part[1023];
}

__global__ __launch_bounds__(256) void scatter_kernel(const int* __restrict__ src,
                                                      const int* __restrict__ dst, int E,
                                                      int* __restrict__ cursor,
                                                      int* __restrict__ eid_s,
                                                      int* __restrict__ src_s) {
  int e = blockIdx.x * 256 + threadIdx.x;
  if (e >= E) return;
  int d = dst[e];
  int pos = atomicAdd(&cursor[d], 1);
  eid_s[pos] = e;
  src_s[pos] = src[e];
}

__global__ __launch_bounds__(256) void nm_hist_kernel(const int* __restrict__ n2m,
                                                      const int* __restrict__ batch,
                                                      const int* __restrict__ partial, int N,
                                                      int* __restrict__ counts) {
  int n = blockIdx.x * 256 + threadIdx.x;
  if (n < N) atomicAdd(&counts[n2m[n] + partial[batch[n]]], 1);
}

__global__ __launch_bounds__(256) void nm_scatter_kernel(const int* __restrict__ n2m,
                                                         const int* __restrict__ batch,
                                                         const int* __restrict__ partial, int N,
                                                         int* __restrict__ cursor,
                                                         int* __restrict__ node_s) {
  int n = blockIdx.x * 256 + threadIdx.x;
  if (n >= N) return;
  int m = n2m[n] + partial[batch[n]];
  node_s[atomicAdd(&cursor[m], 1)] = n;
}

// ---- GINE pull-aggregate fused with self: h[n,d] = x[n,d] + sum_e relu(x[src_e,d]+ea[e,d]) ----
__global__ __launch_bounds__(128) void gine_agg_kernel(
    const float* __restrict__ x, const float* __restrict__ ea,
    const int* __restrict__ base, const int* __restrict__ eid_s,
    const int* __restrict__ src_s, float* __restrict__ h, int N) {
  const int n = blockIdx.x * 2 + (threadIdx.x >> 6);
  if (n >= N) return;
  const int d2 = (threadIdx.x & 63) * 2;
  const int e0 = base[n], e1 = base[n + 1];
  float sx = 0.f, sy = 0.f;
  int j = e0;
  for (; j + 1 < e1; j += 2) {
    int eA = eid_s[j],     sA = src_s[j];
    int eB = eid_s[j + 1], sB = src_s[j + 1];
    float2 xa = *(const float2*)&x[sA * 128 + d2];
    float2 ja = *(const float2*)&ea[(long long)eA * 128 + d2];
    float2 xb = *(const float2*)&x[sB * 128 + d2];
    float2 jb = *(const float2*)&ea[(long long)eB * 128 + d2];
    sx += fmaxf(xa.x + ja.x, 0.f) + fmaxf(xb.x + jb.x, 0.f);
    sy += fmaxf(xa.y + ja.y, 0.f) + fmaxf(xb.y + jb.y, 0.f);
  }
  if (j < e1) {
    float2 xa = *(const float2*)&x[src_s[j] * 128 + d2];
    float2 ja = *(const float2*)&ea[(long long)eid_s[j] * 128 + d2];
    sx += fmaxf(xa.x + ja.x, 0.f);
    sy += fmaxf(xa.y + ja.y, 0.f);
  }
  float2 xv = *(const float2*)&x[n * 128 + d2];
  *(float2*)&h[n * 128 + d2] = make_float2(xv.x + sx, xv.y + sy);
}

// ---- GIN pull-aggregate fused with self ----
__global__ __launch_bounds__(128) void gin_agg_kernel(
    const float* __restrict__ hi, const int* __restrict__ base,
    const int* __restrict__ src_s, float* __restrict__ ho, int M) {
  const int m = blockIdx.x * 2 + (threadIdx.x >> 6);
  if (m >= M) return;
  const int d2 = (threadIdx.x & 63) * 2;
  const int e0 = base[m], e1 = base[m + 1];
  float sx = 0.f, sy = 0.f;
  int j = e0;
  for (; j + 1 < e1; j += 2) {
    float2 a = *(const float2*)&hi[src_s[j] * 128 + d2];
    float2 b = *(const float2*)&hi[src_s[j + 1] * 128 + d2];
    sx += a.x + b.x; sy += a.y + b.y;
  }
  if (j < e1) {
    float2 a = *(const float2*)&hi[src_s[j] * 128 + d2];
    sx += a.x; sy += a.y;
  }
  float2 hv = *(const float2*)&hi[m * 128 + d2];
  *(float2*)&ho[m * 128 + d2] = make_float2(hv.x + sx, hv.y + sy);
}

// ---- motif gather: xm_h[m,d] = emb[motifid[m],d] + sum_{nodes in m} xm_nodes[node,d] ----
__global__ __launch_bounds__(128) void motif_gather_kernel(
    const float* __restrict__ xm_nodes, const int* __restrict__ mb,
    const int* __restrict__ node_s, const int* __restrict__ motifid,
    const float* __restrict__ emb, float* __restrict__ xm_h, int M) {
  const int m = blockIdx.x * 2 + (threadIdx.x >> 6);
  if (m >= M) return;
  const int d2 = (threadIdx.x & 63) * 2;
  float2 e = *(const float2*)&emb[motifid[m] * 128 + d2];
  float sx = e.x, sy = e.y;
  const int j0 = mb[m], j1 = mb[m + 1];
  int j = j0;
  for (; j + 1 < j1; j += 2) {
    float2 a = *(const float2*)&xm_nodes[(long long)node_s[j] * 128 + d2];
    float2 b = *(const float2*)&xm_nodes[(long long)node_s[j + 1] * 128 + d2];
    sx += a.x + b.x; sy += a.y + b.y;
  }
  if (j < j1) {
    float2 a = *(const float2*)&xm_nodes[(long long)node_s[j] * 128 + d2];
    sx += a.x; sy += a.y;
  }
  *(float2*)&xm_h[m * 128 + d2] = make_float2(sx, sy);
}

// ---------------- weight preconversion: fp32 [128][128] -> fragment-ordered bf16 hi/lo ----------------
// Layout per matrix (32768 ushorts): hi plane [kc][nt][lane][8] (16384), then lo plane (16384).
struct WSrc { const float* p[13]; };

__global__ __launch_bounds__(256) void convw_kernel(WSrc wsrc, ushort* __restrict__ Wf) {
  const int mat = blockIdx.x >> 2;
  const int kc  = blockIdx.x & 3;
  const float* W = wsrc.p[mat];
  const int t = threadIdx.x;
  #pragma unroll
  for (int i = 0; i < 16; ++i) {
    int o = t * 16 + i;                    // 0..4095
    int nt = o >> 9, lane = (o >> 3) & 63, j = o & 7;
    int k = kc * 32 + (lane >> 4) * 8 + j;
    int n = nt * 16 + (lane & 15);
    unsigned hi, lo;
    split_bf(W[k * 128 + n], hi, lo);
    Wf[mat * 32768 + kc * 4096 + o]         = (ushort)hi;
    Wf[mat * 32768 + 16384 + kc * 4096 + o] = (ushort)lo;
  }
}

// ---------------- MFMA GEMM core (128x128 tile, 4 waves, 64x64 per wave) ----------------
// A in LDS bf16 planes, XOR-swizzled: byte = row*256 + ((k*2) ^ ((row&7)<<4))
__device__ __forceinline__ void stage_a_bf(ushort* AsH, ushort* AsL,
                                           const float* __restrict__ src,
                                           int row0, int nrows, int tid) {
  #pragma unroll
  for (int it = 0; it < 16; ++it) {
    int idx = (it * 256 + tid) * 4;
    int r = idx >> 7, k = idx & 127;
    float4 v = make_float4(0.f, 0.f, 0.f, 0.f);
    if (row0 + r < nrows) v = *(const float4*)&src[(long long)(row0 + r) * 128 + k];
    unsigned h0, l0, h1, l1, h2, l2, h3, l3;
    split_bf(v.x, h0, l0); split_bf(v.y, h1, l1);
    split_bf(v.z, h2, l2); split_bf(v.w, h3, l3);
    uint2 ph = make_uint2(h0 | (h1 << 16), h2 | (h3 << 16));
    uint2 pl = make_uint2(l0 | (l1 << 16), l2 | (l3 << 16));
    int boff = r * 256 + ((k * 2) ^ ((r & 7) << 4));
    *(uint2*)((char*)AsH + boff) = ph;
    *(uint2*)((char*)AsL + boff) = pl;
  }
}

__device__ __forceinline__ bf16x8 ld_afrag(const ushort* As, int row, int k0) {
  int boff = row * 256 + ((k0 * 2) ^ ((row & 7) << 4));
  return *(const bf16x8*)((const char*)As + boff);
}

__device__ __forceinline__ bf16x8 ld_wfrag(const ushort* Wf, int kc, int nt, int lane) {
  return ((const bf16x8*)Wf)[(kc * 8 + nt) * 64 + lane];
}

// acc += A * W  (3-pass hi/lo: hh + hl + lh)
__device__ __forceinline__ void mfma_gemm(const ushort* AsH, const ushort* AsL,
                                          const ushort* WfH, const ushort* WfL,
                                          int wr, int wc, int lane, f32x4 (&acc)[4][4]) {
  #pragma unroll
  for (int kc = 0; kc < 4; ++kc) {
    const int k0 = kc * 32 + (lane >> 4) * 8;
    bf16x8 ah[4], al[4], wh[4], wl[4];
    #pragma unroll
    for (int rt = 0; rt < 4; ++rt) {
      int row = wr * 64 + rt * 16 + (lane & 15);
      ah[rt] = ld_afrag(AsH, row, k0);
      al[rt] = ld_afrag(AsL, row, k0);
    }
    #pragma unroll
    for (int ct = 0; ct < 4; ++ct) {
      int nt = wc * 4 + ct;
      wh[ct] = ld_wfrag(WfH, kc, nt, lane);
      wl[ct] = ld_wfrag(WfL, kc, nt, lane);
    }
    #pragma unroll
    for (int rt = 0; rt < 4; ++rt)
      #pragma unroll
      for (int ct = 0; ct < 4; ++ct) {
        acc[rt][ct] = __builtin_amdgcn_mfma_f32_16x16x32_bf16(ah[rt], wh[ct], acc[rt][ct], 0, 0, 0);
        acc[rt][ct] = __builtin_amdgcn_mfma_f32_16x16x32_bf16(ah[rt], wl[ct], acc[rt][ct], 0, 0, 0);
        acc[rt][ct] = __builtin_amdgcn_mfma_f32_16x16x32_bf16(al[rt], wh[ct], acc[rt][ct], 0, 0, 0);
      }
  }
}

__device__ __forceinline__ void bias_acc(f32x4 (&acc)[4][4], const float* __restrict__ b,
                                         int wc, int lane) {
  #pragma unroll
  for (int ct = 0; ct < 4; ++ct) {
    float bv = b[wc * 64 + ct * 16 + (lane & 15)];
    #pragma unroll
    for (int rt = 0; rt < 4; ++rt) acc[rt][ct] = (f32x4){bv, bv, bv, bv};
  }
}

// out = relu( relu(h@W1 + b1) @ W2 + b2 ), fused two GEMMs (H kept in LDS)
__global__ __launch_bounds__(256, 2) void mlp_mfma_kernel(
    const float* __restrict__ h,
    const ushort* __restrict__ W1f, const float* __restrict__ b1,
    const ushort* __restrict__ W2f, const float* __restrict__ b2,
    float* __restrict__ out, int nrows) {
  __shared__ ushort AsH[128 * 128];
  __shared__ ushort AsL[128 * 128];
  const int tid = threadIdx.x;
  const int lane = tid & 63;
  const int w = tid >> 6;
  const int wr = w >> 1, wc = w & 1;
  const int row0 = blockIdx.x * 128;

  stage_a_bf(AsH, AsL, h, row0, nrows, tid);
  __syncthreads();

  f32x4 acc[4][4];
  bias_acc(acc, b1, wc, lane);
  mfma_gemm(AsH, AsL, W1f, W1f + 16384, wr, wc, lane, acc);
  __syncthreads();   // all waves done reading As

  // H = relu(acc) -> As planes (bf16 hi/lo, swizzled)
  #pragma unroll
  for (int rt = 0; rt < 4; ++rt)
    #pragma unroll
    for (int ct = 0; ct < 4; ++ct) {
      int col = wc * 64 + ct * 16 + (lane & 15);
      #pragma unroll
      for (int r = 0; r < 4; ++r) {
        int row = wr * 64 + rt * 16 + (lane >> 4) * 4 + r;
        unsigned hi, lo;
        split_bf(fmaxf(acc[rt][ct][r], 0.f), hi, lo);
        int boff = row * 256 + ((col * 2) ^ ((row & 7) << 4));
        *(ushort*)((char*)AsH + boff) = (ushort)hi;
        *(ushort*)((char*)AsL + boff) = (ushort)lo;
      }
    }
  __syncthreads();

  f32x4 acc2[4][4];
  bias_acc(acc2, b2, wc, lane);
  mfma_gemm(AsH, AsL, W2f, W2f + 16384, wr, wc, lane, acc2);

  #pragma unroll
  for (int rt = 0; rt < 4; ++rt)
    #pragma unroll
    for (int ct = 0; ct < 4; ++ct) {
      int col = wc * 64 + ct * 16 + (lane & 15);
      #pragma unroll
      for (int r = 0; r < 4; ++r) {
        int row = row0 + wr * 64 + rt * 16 + (lane >> 4) * 4 + r;
        if (row < nrows) out[(long long)row * 128 + col] = fmaxf(acc2[rt][ct][r], 0.f);
      }
    }
}

// xm_nodes = relu([x1|x2|x3] @ lin_W + lin_b), K=384 via 3 staged chunks
__global__ __launch_bounds__(256, 2) void lin_mfma_kernel(
    const float* __restrict__ x1, const float* __restrict__ x2, const float* __restrict__ x3,
    const ushort* __restrict__ Wlf, const float* __restrict__ lb,
    float* __restrict__ xm_nodes, int nrows) {
  __shared__ ushort AsH[128 * 128];
  __shared__ ushort AsL[128 * 128];
  const int tid = threadIdx.x;
  const int lane = tid & 63;
  const int w = tid >> 6;
  const int wr = w >> 1, wc = w & 1;
  const int row0 = blockIdx.x * 128;

  f32x4 acc[4][4];
  bias_acc(acc, lb, wc, lane);

  for (int c3 = 0; c3 < 3; ++c3) {
    const float* xs = (c3 == 0) ? x1 : (c3 == 1 ? x2 : x3);
    if (c3) __syncthreads();
    stage_a_bf(AsH, AsL, xs, row0, nrows, tid);
    __syncthreads();
    const ushort* Wc = Wlf + c3 * 32768;
    mfma_gemm(AsH, AsL, Wc, Wc + 16384, wr, wc, lane, acc);
  }

  #pragma unroll
  for (int rt = 0; rt < 4; ++rt)
    #pragma unroll
    for (int ct = 0; ct < 4; ++ct) {
      int col = wc * 64 + ct * 16 + (lane & 15);
      #pragma unroll
      for (int r = 0; r < 4; ++r) {
        int row = row0 + wr * 64 + rt * 16 + (lane >> 4) * 4 + r;
        if (row < nrows) xm_nodes[(long long)row * 128 + col] = fmaxf(acc[rt][ct][r], 0.f);
      }
    }
}

// chunked node pooling over sorted batch[]
__global__ __launch_bounds__(192) void xg_pool_kernel(
    const float* __restrict__ x1, const float* __restrict__ x2, const float* __restrict__ x3,
    const int* __restrict__ batch, int N, int chunk, float* __restrict__ outg) {
  const int c0 = blockIdx.x * chunk;
  if (c0 >= N) return;
  const int c1 = min(c0 + chunk, N);
  const int l = threadIdx.x >> 6;
  const int d2 = (threadIdx.x & 63) * 2;
  const float* xs = (l == 0) ? x1 : (l == 1 ? x2 : x3);
  int b = batch[c0];
  float sx = 0.f, sy = 0.f;
  for (int n = c0; n < c1; ++n) {
    int bn = batch[n];
    if (bn != b) {
      if (sx != 0.f) atomicAdd(&outg[b * 384 + l * 128 + d2], sx);
      if (sy != 0.f) atomicAdd(&outg[b * 384 + l * 128 + d2 + 1], sy);
      sx = 0.f; sy = 0.f; b = bn;
    }
    float2 v = *(const float2*)&xs[n * 128 + d2];
    sx += v.x; sy += v.y;
  }
  atomicAdd(&outg[b * 384 + l * 128 + d2], sx);
  atomicAdd(&outg[b * 384 + l * 128 + d2 + 1], sy);
}

// chunked motif pooling
__global__ __launch_bounds__(128) void xm_pool_kernel(
    const float* __restrict__ m1, const float* __restrict__ m2,
    const int* __restrict__ partial, int B, int M, int chunk,
    float* __restrict__ outm) {
  const int c0 = blockIdx.x * chunk;
  if (c0 >= M) return;
  const int c1 = min(c0 + chunk, M);
  const int l = threadIdx.x >> 6;
  const int d2 = (threadIdx.x & 63) * 2;
  const float* ms = (l == 0) ? m1 : m2;
  int b = 0;
  while (b + 1 < B && partial[b + 1] <= c0) ++b;
  int bend = (b + 1 < B) ? partial[b + 1] : M;
  float sx = 0.f, sy = 0.f;
  for (int m = c0; m < c1; ++m) {
    if (m >= bend) {
      if (sx != 0.f) atomicAdd(&outm[b * 256 + l * 128 + d2], sx);
      if (sy != 0.f) atomicAdd(&outm[b * 256 + l * 128 + d2 + 1], sy);
      sx = 0.f; sy = 0.f;
      do { ++b; } while (b + 1 < B && partial[b + 1] <= m);
      bend = (b + 1 < B) ? partial[b + 1] : M;
    }
    float2 v = *(const float2*)&ms[m * 128 + d2];
    sx += v.x; sy += v.y;
  }
  atomicAdd(&outm[b * 256 + l * 128 + d2], sx);
  atomicAdd(&outm[b * 256 + l * 128 + d2 + 1], sy);
}

extern "C" void kernel_launch(void* const* d_in, const int* in_sizes, int n_in,
                              void* d_out, int out_size, void* d_ws, size_t ws_size,
                              hipStream_t stream) {
  const float* x       = (const float*)d_in[0];
  const float* ea      = (const float*)d_in[1];
  const int*   eidx    = (const int*)d_in[2];
  const int*   batch   = (const int*)d_in[3];
  const int*   n2m     = (const int*)d_in[4];
  const int*   nmot    = (const int*)d_in[5];
  const int*   meidx   = (const int*)d_in[6];
  const int*   motifid = (const int*)d_in[7];
  const float* gcW1 = (const float*)d_in[8];
  const float* gcb1 = (const float*)d_in[9];
  const float* gcW2 = (const float*)d_in[10];
  const float* gcb2 = (const float*)d_in[11];
  const float* mcW1 = (const float*)d_in[12];
  const float* mcb1 = (const float*)d_in[13];
  const float* mcW2 = (const float*)d_in[14];
  const float* mcb2 = (const float*)d_in[15];
  const float* linW = (const float*)d_in[16];
  const float* linb = (const float*)d_in[17];
  const float* emb  = (const float*)d_in[18];
  float* outp = (float*)d_out;

  const int N  = in_sizes[0] / 128;   // 50000
  const int E  = in_sizes[1] / 128;   // 600000
  const int B  = in_sizes[5];         // 64
  const int ME = in_sizes[6] / 2;     // 50000
  const int M  = in_sizes[7];         // 6400

  const size_t nodeBytes = (size_t)N * 128 * 4;
  const size_t motBytes  = (size_t)M * 128 * 4;
  char* ws = (char*)d_ws;
  float* xl0 = (float*)ws;                 ws += nodeBytes;
  float* xl1 = (float*)ws;                 ws += nodeBytes;
  float* xl2 = (float*)ws;                 ws += nodeBytes;
  char*  R   = ws;                         ws += nodeBytes;   // h during GINE; xm_nodes after
  ushort* Wf = (ushort*)ws;                ws += (size_t)13 * 32768 * 2;   // 832 KB frag-ordered weights
  int* counts  = (int*)ws;                 ws += (size_t)N * 4;
  int* base    = (int*)ws;                 ws += (size_t)(N + 1) * 4;
  int* cursor  = (int*)ws;                 ws += (size_t)N * 4;
  int* eid_s   = (int*)ws;                 ws += (size_t)E * 4;
  int* src_s   = (int*)ws;                 ws += (size_t)E * 4;
  int* mcounts = (int*)ws;                 ws += (size_t)M * 4;
  int* mbase   = (int*)ws;                 ws += (size_t)(M + 1) * 4;
  int* mcursor = (int*)ws;                 ws += (size_t)M * 4;
  int* meid_s  = (int*)ws;                 ws += (size_t)ME * 4;
  int* msrc_s  = (int*)ws;                 ws += (size_t)ME * 4;
  int* nmcnt   = (int*)ws;                 ws += (size_t)M * 4;
  int* nmbase  = (int*)ws;                 ws += (size_t)(M + 1) * 4;
  int* nmcur   = (int*)ws;                 ws += (size_t)M * 4;
  int* node_s  = (int*)ws;                 ws += (size_t)N * 4;
  int* partial = (int*)ws;                 ws += 256;
  int* bnd     = (int*)ws;                 ws += 512;
  if ((size_t)(ws - (char*)d_ws) > ws_size) return;

  float* hbuf     = (float*)R;
  float* xm_nodes = (float*)R;
  float* xmh = (float*)((char*)xl0);                   // motif buffers after GINE stage
  float* hm  = (float*)((char*)xl0 + motBytes);
  float* ml0 = (float*)((char*)xl0 + 2 * motBytes);
  float* ml1 = (float*)((char*)xl0 + 3 * motBytes);

  hipMemsetAsync(outp, 0, (size_t)out_size * 4, stream);

  prep_kernel<<<1, 128, 0, stream>>>(nmot, batch, N, B, partial, bnd);

  // ---- preconvert all weight matrices to fragment-ordered bf16 hi/lo ----
  WSrc wsrc;
  wsrc.p[0] = gcW1;            wsrc.p[1] = gcW1 + 16384;  wsrc.p[2] = gcW1 + 32768;
  wsrc.p[3] = gcW2;            wsrc.p[4] = gcW2 + 16384;  wsrc.p[5] = gcW2 + 32768;
  wsrc.p[6] = mcW1;            wsrc.p[7] = mcW1 + 16384;
  wsrc.p[8] = mcW2;            wsrc.p[9] = mcW2 + 16384;
  wsrc.p[10] = linW;           wsrc.p[11] = linW + 16384; wsrc.p[12] = linW + 32768;
  convw_kernel<<<52, 256, 0, stream>>>(wsrc, Wf);

  // ---- node-graph CSR by dst ----
  const int* src = eidx;
  const int* dst = eidx + E;
  hipMemsetAsync(counts, 0, (size_t)N * 4, stream);
  hist_kernel<<<(E + 255) / 256, 256, 0, stream>>>(dst, E, counts);
  scan_kernel<<<1, 1024, 0, stream>>>(counts, N, base, cursor);
  scatter_kernel<<<(E + 255) / 256, 256, 0, stream>>>(src, dst, E, cursor, eid_s, src_s);

  // ---- motif-graph CSR by dst ----
  const int* msrc = meidx;
  const int* mdst = meidx + ME;
  hipMemsetAsync(mcounts, 0, (size_t)M * 4, stream);
  hist_kernel<<<(ME + 255) / 256, 256, 0, stream>>>(mdst, ME, mcounts);
  scan_kernel<<<1, 1024, 0, stream>>>(mcounts, M, mbase, mcursor);
  scatter_kernel<<<(ME + 255) / 256, 256, 0, stream>>>(msrc, mdst, ME, mcursor, meid_s, msrc_s);

  // ---- node->motif CSR ----
  hipMemsetAsync(nmcnt, 0, (size_t)M * 4, stream);
  nm_hist_kernel<<<(N + 255) / 256, 256, 0, stream>>>(n2m, batch, partial, N, nmcnt);
  scan_kernel<<<1, 1024, 0, stream>>>(nmcnt, M, nmbase, nmcur);
  nm_scatter_kernel<<<(N + 255) / 256, 256, 0, stream>>>(n2m, batch, partial, N, nmcur, node_s);

  // ---- GINE stack ----
  const float* xs[3] = {x, xl0, xl1};
  float* xo[3] = {xl0, xl1, xl2};
  const int ngrid = (N + 127) / 128;
  for (int i = 0; i < 3; ++i) {
    gine_agg_kernel<<<(N + 1) / 2, 128, 0, stream>>>(xs[i], ea, base, eid_s, src_s, hbuf, N);
    mlp_mfma_kernel<<<ngrid, 256, 0, stream>>>(hbuf,
        Wf + (size_t)(0 + i) * 32768, gcb1 + i * 128,
        Wf + (size_t)(3 + i) * 32768, gcb2 + i * 128, xo[i], N);
  }
  {
    const int nb = 512;
    const int chunk = (N + nb - 1) / nb;
    xg_pool_kernel<<<nb, 192, 0, stream>>>(xl0, xl1, xl2, batch, N, chunk, outp + B * 256);
  }

  // ---- motif features: lin (no atomics) then CSR gather (+emb fused) ----
  lin_mfma_kernel<<<ngrid, 256, 0, stream>>>(xl0, xl1, xl2, Wf + (size_t)10 * 32768, linb,
                                             xm_nodes, N);
  motif_gather_kernel<<<(M + 1) / 2, 128, 0, stream>>>(xm_nodes, nmbase, node_s,
                                                       motifid, emb, xmh, M);

  // ---- motif GIN stack ----
  const float* hs[2] = {xmh, ml0};
  float* mo[2] = {ml0, ml1};
  const int mgrid = (M + 127) / 128;
  for (int i = 0; i < 2; ++i) {
    gin_agg_kernel<<<(M + 1) / 2, 128, 0, stream>>>(hs[i], mbase, msrc_s, hm, M);
    mlp_mfma_kernel<<<mgrid, 256, 0, stream>>>(hm,
        Wf + (size_t)(6 + i) * 32768, mcb1 + i * 128,
        Wf + (size_t)(8 + i) * 32768, mcb2 + i * 128, mo[i], M);
  }
  {
    const int nb = 256;
    const int chunk = (M + nb - 1) / nb;
    xm_pool_kernel<<<nb, 128, 0, stream>>>(ml0, ml1, partial, B, M, chunk, outp);
  }
}